// Round 3
// baseline (461.431 us; speedup 1.0000x reference)
//
#include <hip/hip_runtime.h>
#include <math.h>

#define BB 8
#define CC 1024
#define LL 4096
#define NPB (CC*LL)          // 4194304 elements per batch
#define LT 16                // l-tile per fused block

typedef float f32x4 __attribute__((ext_vector_type(4)));

// ws layout:
//   [0,128)    double sums[16]      (S1,S2 per batch)
//   [128,136)  double lossAcc

// grid (256, 8) x 256 threads. Each thread: 16 float4 of xt, strided, unroll 4.
__global__ void k_batch_sums(const float* __restrict__ xt, double* __restrict__ sums) {
    int b = blockIdx.y;
    const float4* p = (const float4*)(xt + (size_t)b * NPB);
    int t = blockIdx.x * blockDim.x + threadIdx.x;      // [0, 65536)
    double s1 = 0.0, s2 = 0.0;
    #pragma unroll
    for (int j4 = 0; j4 < 4; ++j4) {
        float4 v[4];
        #pragma unroll
        for (int k = 0; k < 4; ++k) v[k] = p[(size_t)(j4 * 4 + k) * 65536 + t];
        #pragma unroll
        for (int k = 0; k < 4; ++k) {
            float q1 = (v[k].x + v[k].y) + (v[k].z + v[k].w);
            float q2 = (v[k].x * v[k].x + v[k].y * v[k].y)
                     + (v[k].z * v[k].z + v[k].w * v[k].w);
            s1 += (double)q1;
            s2 += (double)q2;
        }
    }
    for (int off = 32; off; off >>= 1) {
        s1 += __shfl_down(s1, off, 64);
        s2 += __shfl_down(s2, off, 64);
    }
    __shared__ double ls1[4], ls2[4];
    int lane = threadIdx.x & 63, w = threadIdx.x >> 6;
    if (lane == 0) { ls1[w] = s1; ls2[w] = s2; }
    __syncthreads();
    if (threadIdx.x == 0) {
        atomicAdd(&sums[2 * b],     ls1[0] + ls1[1] + ls1[2] + ls1[3]);
        atomicAdd(&sums[2 * b + 1], ls2[0] + ls2[1] + ls2[2] + ls2[3]);
    }
}

// Fused colstats + entropy, LDS-payload variant.
// grid (LL/LT=256, 8) x 512 threads (8 waves). Block owns (b, l in [L0,L0+16))
// for ALL C=1024 channels. Thread: q=tid&3 -> l-quad; g=tid>>2 -> c=g+128i, i<8.
// Per c, 4 consecutive lanes x float4 = 64 B contiguous segments.
// Pass 1: load xs,xt once; exp(xs) -> LDS (64 KiB, conflict-free: each wave's
// ds_write_b128 covers one contiguous 1024 B region); accumulate column sums.
// Pass 2: exp(xs) from LDS; y=max(xt,mg) from an L2/L3-resident re-read of xt
// (reverse i order = LRU-friendly); nontemporal store of entropy.
// ~67 KiB LDS -> 2 blocks/CU: the co-resident block covers barrier stalls.
__global__ __launch_bounds__(512, 4)
void k_fused(const float* __restrict__ xs, const float* __restrict__ xt,
             const double* __restrict__ sums,
             float* __restrict__ out1, double* __restrict__ lossAcc) {
    int tid = threadIdx.x;
    int b = blockIdx.y;
    int L0 = blockIdx.x * LT;
    int q = tid & 3;            // l-quad within tile
    int g = tid >> 2;           // c-group [0,128)
    int lane = tid & 63, w = tid >> 6;

    __shared__ float s_mg;
    __shared__ __align__(16) float s_es[CC * LT];        // 64 KiB: [c][l], addr c*16+q*4+k
    __shared__ __align__(16) float s_red[2][8][4][4];    // [arr][wave][q][k]
    __shared__ __align__(16) float s_sinv[4][4];
    __shared__ __align__(16) float s_blog[4][4];
    __shared__ float wacc[8];

    if (tid == 0) {
        // inline margin from batch sums (double precision, ddof=1)
        double n = (double)NPB;
        double s1 = sums[2 * b], s2 = sums[2 * b + 1];
        double mean = s1 / n;
        double var = (s2 - s1 * s1 / n) / (n - 1.0);
        double sd = sqrt(var);
        double z = -mean / sd;
        double cdf = 0.5 * (1.0 + erf(z / 1.4142135623730951));
        double safe = fmax(cdf, 1e-30);
        double r = mean / sd;
        double ma = -sd * exp(-r * r * 0.5) / 2.5066282746310002 / safe + mean;
        s_mg = (float)((cdf > 0.001) ? ma : -3.0 * sd);
    }
    __syncthreads();
    float mg = s_mg;

    const float* ps = xs + (size_t)b * NPB + L0 + q * 4;
    const float* pt = xt + (size_t)b * NPB + L0 + q * 4;

    float ss[4] = {0, 0, 0, 0}, sy[4] = {0, 0, 0, 0};
    #pragma unroll
    for (int i = 0; i < 8; ++i) {
        int c = g + 128 * i;
        size_t off = (size_t)c * LL;
        float4 s4 = *(const float4*)(ps + off);
        float4 t4 = *(const float4*)(pt + off);
        float4 e;
        e.x = __expf(s4.x); e.y = __expf(s4.y); e.z = __expf(s4.z); e.w = __expf(s4.w);
        *(float4*)&s_es[c * LT + q * 4] = e;
        ss[0] += e.x; ss[1] += e.y; ss[2] += e.z; ss[3] += e.w;
        sy[0] += __expf(fmaxf(t4.x, mg)); sy[1] += __expf(fmaxf(t4.y, mg));
        sy[2] += __expf(fmaxf(t4.z, mg)); sy[3] += __expf(fmaxf(t4.w, mg));
    }
    // reduce over c within the wave: same-q lanes are lane = q + 4*gg
    #pragma unroll
    for (int off = 4; off < 64; off <<= 1) {
        #pragma unroll
        for (int k = 0; k < 4; ++k) {
            ss[k] += __shfl_xor(ss[k], off, 64);
            sy[k] += __shfl_xor(sy[k], off, 64);
        }
    }
    if (lane < 4) {
        #pragma unroll
        for (int k = 0; k < 4; ++k) {
            s_red[0][w][lane][k] = ss[k];
            s_red[1][w][lane][k] = sy[k];
        }
    }
    __syncthreads();
    if (tid < 32) {
        int a  = tid >> 4;          // 0 = ss, 1 = sy
        int qq = (tid >> 2) & 3;
        int k  = tid & 3;
        float t = 0.f;
        #pragma unroll
        for (int ww = 0; ww < 8; ++ww) t += s_red[a][ww][qq][k];
        if (a == 0) s_sinv[qq][k] = 1.0f / t;      // 1/sum(exp(xs))
        else        s_blog[qq][k] = __logf(t);     // log(sum(exp(y)))
    }
    __syncthreads();
    float4 sinv = *(const float4*)&s_sinv[q][0];
    float4 blog = *(const float4*)&s_blog[q][0];

    float* po = out1 + (size_t)b * NPB + L0 + q * 4;
    float acc = 0.f;
    #pragma unroll
    for (int i = 7; i >= 0; --i) {          // reverse: most-recent lines first
        int c = g + 128 * i;
        size_t off = (size_t)c * LL;
        float4 t4 = *(const float4*)(pt + off);      // L2/L3-resident re-read
        float4 ev = *(const float4*)&s_es[c * LT + q * 4];
        f32x4 e;
        e.x = ev.x * sinv.x * (fmaxf(t4.x, mg) - blog.x);
        e.y = ev.y * sinv.y * (fmaxf(t4.y, mg) - blog.y);
        e.z = ev.z * sinv.z * (fmaxf(t4.z, mg) - blog.z);
        e.w = ev.w * sinv.w * (fmaxf(t4.w, mg) - blog.w);
        // nontemporal: don't let 134 MB of output evict x_st from L3
        __builtin_nontemporal_store(e, (f32x4*)(po + off));
        acc += (e.x + e.y) + (e.z + e.w);
    }
    for (int off = 32; off; off >>= 1) acc += __shfl_down(acc, off, 64);
    if (lane == 0) wacc[w] = acc;
    __syncthreads();
    if (tid == 0) {
        double t = 0.0;
        #pragma unroll
        for (int ww = 0; ww < 8; ++ww) t += (double)wacc[ww];
        atomicAdd(lossAcc, t);
    }
}

__global__ void k_finalize(const double* __restrict__ lossAcc, float* __restrict__ out) {
    if (threadIdx.x == 0) out[0] = (float)(-lossAcc[0] / (double)(BB * LL));
}

extern "C" void kernel_launch(void* const* d_in, const int* in_sizes, int n_in,
                              void* d_out, int out_size, void* d_ws, size_t ws_size,
                              hipStream_t stream) {
    const float* x_ts = (const float*)d_in[2];  // source xs
    const float* x_st = (const float*)d_in[3];  // target xt
    float* out = (float*)d_out;

    double* sums    = (double*)d_ws;
    double* lossAcc = (double*)((char*)d_ws + 128);

    hipMemsetAsync(d_ws, 0, 256, stream);

    k_batch_sums<<<dim3(256, BB), 256, 0, stream>>>(x_st, sums);
    k_fused<<<dim3(LL / LT, BB), 512, 0, stream>>>(x_ts, x_st, sums, out + 1, lossAcc);
    k_finalize<<<1, 64, 0, stream>>>(lossAcc, out);
}

// Round 4
// 428.785 us; speedup vs baseline: 1.0761x; 1.0761x over previous
//
#include <hip/hip_runtime.h>
#include <math.h>

#define BB 8
#define CC 1024
#define LL 4096
#define NPB (CC*LL)          // 4194304 elements per batch
#define LT 32                // l-tile per fused block (32 floats = full 128B lines)

typedef float f32x4 __attribute__((ext_vector_type(4)));

// ws layout:
//   [0,128)    double sums[16]      (S1,S2 per batch)
//   [128,136)  double lossAcc

// grid (256, 8) x 256 threads. Each thread: 16 float4 of xt, strided, unroll 4.
// Side effect we rely on: pulls all of x_st (134 MB) into L3.
__global__ void k_batch_sums(const float* __restrict__ xt, double* __restrict__ sums) {
    int b = blockIdx.y;
    const float4* p = (const float4*)(xt + (size_t)b * NPB);
    int t = blockIdx.x * blockDim.x + threadIdx.x;      // [0, 65536)
    double s1 = 0.0, s2 = 0.0;
    #pragma unroll
    for (int j4 = 0; j4 < 4; ++j4) {
        float4 v[4];
        #pragma unroll
        for (int k = 0; k < 4; ++k) v[k] = p[(size_t)(j4 * 4 + k) * 65536 + t];
        #pragma unroll
        for (int k = 0; k < 4; ++k) {
            float q1 = (v[k].x + v[k].y) + (v[k].z + v[k].w);
            float q2 = (v[k].x * v[k].x + v[k].y * v[k].y)
                     + (v[k].z * v[k].z + v[k].w * v[k].w);
            s1 += (double)q1;
            s2 += (double)q2;
        }
    }
    for (int off = 32; off; off >>= 1) {
        s1 += __shfl_down(s1, off, 64);
        s2 += __shfl_down(s2, off, 64);
    }
    __shared__ double ls1[4], ls2[4];
    int lane = threadIdx.x & 63, w = threadIdx.x >> 6;
    if (lane == 0) { ls1[w] = s1; ls2[w] = s2; }
    __syncthreads();
    if (threadIdx.x == 0) {
        atomicAdd(&sums[2 * b],     ls1[0] + ls1[1] + ls1[2] + ls1[3]);
        atomicAdd(&sums[2 * b + 1], ls2[0] + ls2[1] + ls2[2] + ls2[3]);
    }
}

// Fused colstats + entropy, half-payload variant.
// grid (LL/LT=128, 8) x 1024 threads (16 waves). Block owns (b, l in [L0,L0+32))
// for ALL C=1024 channels. Thread: q=tid&7 -> l-quad; g=tid>>3 -> c=g+128i, i<8.
// Per c, 8 consecutive lanes x float4 = 128 B = exactly one cache line.
// Pass 1: load xs,xt once; keep ONLY es[8]=exp(xs) in registers (32 floats —
// fits the 128-VGPR budget, unlike the 64-float payload that spilled in r1/r2);
// accumulate per-l column sums; reduce via shfl_xor + LDS across 16 waves.
// Pass 2: es from registers; y=max(xt,mg) RECOMPUTED from an xt re-read, which
// is L3-resident (proven r2: FETCH stayed at one array) and partially L2-hot
// (reverse i order re-touches most-recent lines first). Nontemporal stores so
// 134 MB of output doesn't evict xt from L3.
__global__ __launch_bounds__(1024, 4)
void k_fused(const float* __restrict__ xs, const float* __restrict__ xt,
             const double* __restrict__ sums,
             float* __restrict__ out1, double* __restrict__ lossAcc) {
    int tid = threadIdx.x;
    int b = blockIdx.y;
    int L0 = blockIdx.x * LT;
    int q = tid & 7;
    int g = tid >> 3;
    int lane = tid & 63, w = tid >> 6;

    __shared__ float s_mg;
    __shared__ __align__(16) float s_red[2][16][8][4];   // [arr][wave][q][k]
    __shared__ __align__(16) float s_sinv[8][4];
    __shared__ __align__(16) float s_blog[8][4];
    __shared__ float wacc[16];

    if (tid == 0) {
        // inline margin from batch sums (double precision, ddof=1)
        double n = (double)NPB;
        double s1 = sums[2 * b], s2 = sums[2 * b + 1];
        double mean = s1 / n;
        double var = (s2 - s1 * s1 / n) / (n - 1.0);
        double sd = sqrt(var);
        double z = -mean / sd;
        double cdf = 0.5 * (1.0 + erf(z / 1.4142135623730951));
        double safe = fmax(cdf, 1e-30);
        double r = mean / sd;
        double ma = -sd * exp(-r * r * 0.5) / 2.5066282746310002 / safe + mean;
        s_mg = (float)((cdf > 0.001) ? ma : -3.0 * sd);
    }
    __syncthreads();
    float mg = s_mg;

    const float* ps = xs + (size_t)b * NPB + L0 + q * 4;
    const float* pt = xt + (size_t)b * NPB + L0 + q * 4;

    float4 es[8];
    float ss[4] = {0, 0, 0, 0}, sy[4] = {0, 0, 0, 0};
    #pragma unroll
    for (int i = 0; i < 8; ++i) {
        size_t off = (size_t)(g + 128 * i) * LL;
        float4 s4 = *(const float4*)(ps + off);
        float4 t4 = *(const float4*)(pt + off);
        float4 e;
        e.x = __expf(s4.x); e.y = __expf(s4.y); e.z = __expf(s4.z); e.w = __expf(s4.w);
        es[i] = e;
        ss[0] += e.x; ss[1] += e.y; ss[2] += e.z; ss[3] += e.w;
        sy[0] += __expf(fmaxf(t4.x, mg)); sy[1] += __expf(fmaxf(t4.y, mg));
        sy[2] += __expf(fmaxf(t4.z, mg)); sy[3] += __expf(fmaxf(t4.w, mg));
    }
    // reduce across the 8 c-groups inside each wave (same-q lanes: lane = q + 8*gg)
    #pragma unroll
    for (int off = 8; off < 64; off <<= 1) {
        #pragma unroll
        for (int k = 0; k < 4; ++k) {
            ss[k] += __shfl_xor(ss[k], off, 64);
            sy[k] += __shfl_xor(sy[k], off, 64);
        }
    }
    if (lane < 8) {
        #pragma unroll
        for (int k = 0; k < 4; ++k) {
            s_red[0][w][lane][k] = ss[k];
            s_red[1][w][lane][k] = sy[k];
        }
    }
    __syncthreads();
    if (tid < 64) {
        int a  = tid >> 5;          // 0 = ss, 1 = sy
        int qq = (tid >> 2) & 7;
        int k  = tid & 3;
        float t = 0.f;
        #pragma unroll
        for (int ww = 0; ww < 16; ++ww) t += s_red[a][ww][qq][k];
        if (a == 0) s_sinv[qq][k] = 1.0f / t;      // 1/sum(exp(xs))
        else        s_blog[qq][k] = __logf(t);     // log(sum(exp(y)))
    }
    __syncthreads();
    float4 sinv = *(const float4*)&s_sinv[q][0];
    float4 blog = *(const float4*)&s_blog[q][0];

    float* po = out1 + (size_t)b * NPB + L0 + q * 4;
    float acc = 0.f;
    #pragma unroll
    for (int i = 7; i >= 0; --i) {          // reverse: most-recent lines first
        size_t off = (size_t)(g + 128 * i) * LL;
        float4 t4 = *(const float4*)(pt + off);      // L3/L2-resident re-read
        f32x4 e;
        e.x = es[i].x * sinv.x * (fmaxf(t4.x, mg) - blog.x);
        e.y = es[i].y * sinv.y * (fmaxf(t4.y, mg) - blog.y);
        e.z = es[i].z * sinv.z * (fmaxf(t4.z, mg) - blog.z);
        e.w = es[i].w * sinv.w * (fmaxf(t4.w, mg) - blog.w);
        __builtin_nontemporal_store(e, (f32x4*)(po + off));
        acc += (e.x + e.y) + (e.z + e.w);
    }
    for (int off = 32; off; off >>= 1) acc += __shfl_down(acc, off, 64);
    if (lane == 0) wacc[w] = acc;
    __syncthreads();
    if (tid == 0) {
        double t = 0.0;
        #pragma unroll
        for (int ww = 0; ww < 16; ++ww) t += (double)wacc[ww];
        atomicAdd(lossAcc, t);
    }
}

__global__ void k_finalize(const double* __restrict__ lossAcc, float* __restrict__ out) {
    if (threadIdx.x == 0) out[0] = (float)(-lossAcc[0] / (double)(BB * LL));
}

extern "C" void kernel_launch(void* const* d_in, const int* in_sizes, int n_in,
                              void* d_out, int out_size, void* d_ws, size_t ws_size,
                              hipStream_t stream) {
    const float* x_ts = (const float*)d_in[2];  // source xs
    const float* x_st = (const float*)d_in[3];  // target xt
    float* out = (float*)d_out;

    double* sums    = (double*)d_ws;
    double* lossAcc = (double*)((char*)d_ws + 128);

    hipMemsetAsync(d_ws, 0, 256, stream);

    k_batch_sums<<<dim3(256, BB), 256, 0, stream>>>(x_st, sums);
    k_fused<<<dim3(LL / LT, BB), 1024, 0, stream>>>(x_ts, x_st, sums, out + 1, lossAcc);
    k_finalize<<<1, 64, 0, stream>>>(lossAcc, out);
}

// Round 5
// 407.035 us; speedup vs baseline: 1.1336x; 1.0534x over previous
//
#include <hip/hip_runtime.h>
#include <math.h>

#define BB 8
#define CC 1024
#define LL 4096
#define NPB (CC*LL)          // 4194304 elements per batch
#define LT 32                // l-tile per fused block (32 floats = full 128B lines)

typedef float f32x4 __attribute__((ext_vector_type(4)));

// ws layout:
//   [0,128)    double sums[16]      (S1,S2 per batch)
//   [128,136)  double lossAcc

// grid (256, 8) x 256 threads. Each thread: 16 float4 of xt, strided, unroll 4.
// Side effect we rely on: pulls all of x_st (134 MB) into L3.
__global__ void k_batch_sums(const float* __restrict__ xt, double* __restrict__ sums) {
    int b = blockIdx.y;
    const float4* p = (const float4*)(xt + (size_t)b * NPB);
    int t = blockIdx.x * blockDim.x + threadIdx.x;      // [0, 65536)
    double s1 = 0.0, s2 = 0.0;
    #pragma unroll
    for (int j4 = 0; j4 < 4; ++j4) {
        float4 v[4];
        #pragma unroll
        for (int k = 0; k < 4; ++k) v[k] = p[(size_t)(j4 * 4 + k) * 65536 + t];
        #pragma unroll
        for (int k = 0; k < 4; ++k) {
            float q1 = (v[k].x + v[k].y) + (v[k].z + v[k].w);
            float q2 = (v[k].x * v[k].x + v[k].y * v[k].y)
                     + (v[k].z * v[k].z + v[k].w * v[k].w);
            s1 += (double)q1;
            s2 += (double)q2;
        }
    }
    for (int off = 32; off; off >>= 1) {
        s1 += __shfl_down(s1, off, 64);
        s2 += __shfl_down(s2, off, 64);
    }
    __shared__ double ls1[4], ls2[4];
    int lane = threadIdx.x & 63, w = threadIdx.x >> 6;
    if (lane == 0) { ls1[w] = s1; ls2[w] = s2; }
    __syncthreads();
    if (threadIdx.x == 0) {
        atomicAdd(&sums[2 * b],     ls1[0] + ls1[1] + ls1[2] + ls1[3]);
        atomicAdd(&sums[2 * b + 1], ls2[0] + ls2[1] + ls2[2] + ls2[3]);
    }
}

// Fused colstats + entropy.
// grid (LL/LT=128, 8) x 1024 threads (16 waves). Block owns (b, l in [L0,L0+32))
// for ALL C=1024 channels. Thread: q=tid&7 -> l-quad; g=tid>>3 -> c=g+128i, i<8.
// Per c, 8 consecutive lanes x float4 = 128 B = exactly one cache line.
//
// amdgpu_waves_per_eu(4,4): pins occupancy at EXACTLY 4 waves/EU -> VGPR budget
// 128. (__launch_bounds__(.,4) is only a MINIMUM: r1/r2/r4 all show the
// allocator targeting 8 waves/EU = 64 VGPR and spilling 32B/thread to scratch
// -- the recurring +33MB on WRITE_SIZE.)
//
// Pass 1: NT-load xs (read-once, keep it OUT of L3 so xt stays resident),
// regular-load xt; keep es[8]=exp(xs) in registers (32 floats); column sums
// via shfl_xor + LDS across 16 waves.
// Pass 2: es from registers; y=max(xt,mg) recomputed from the L3-resident xt
// re-read (reverse i order = most-recent lines first); NT store of entropy.
__global__ __attribute__((amdgpu_flat_work_group_size(1024, 1024), amdgpu_waves_per_eu(4, 4)))
void k_fused(const float* __restrict__ xs, const float* __restrict__ xt,
             const double* __restrict__ sums,
             float* __restrict__ out1, double* __restrict__ lossAcc) {
    int tid = threadIdx.x;
    int b = blockIdx.y;
    int L0 = blockIdx.x * LT;
    int q = tid & 7;
    int g = tid >> 3;
    int lane = tid & 63, w = tid >> 6;

    __shared__ float s_mg;
    __shared__ __align__(16) float s_red[2][16][8][4];   // [arr][wave][q][k]
    __shared__ __align__(16) float s_sinv[8][4];
    __shared__ __align__(16) float s_blog[8][4];
    __shared__ float wacc[16];

    if (tid == 0) {
        // inline margin from batch sums (double precision, ddof=1)
        double n = (double)NPB;
        double s1 = sums[2 * b], s2 = sums[2 * b + 1];
        double mean = s1 / n;
        double var = (s2 - s1 * s1 / n) / (n - 1.0);
        double sd = sqrt(var);
        double z = -mean / sd;
        double cdf = 0.5 * (1.0 + erf(z / 1.4142135623730951));
        double safe = fmax(cdf, 1e-30);
        double r = mean / sd;
        double ma = -sd * exp(-r * r * 0.5) / 2.5066282746310002 / safe + mean;
        s_mg = (float)((cdf > 0.001) ? ma : -3.0 * sd);
    }
    __syncthreads();
    float mg = s_mg;

    const float* ps = xs + (size_t)b * NPB + L0 + q * 4;
    const float* pt = xt + (size_t)b * NPB + L0 + q * 4;

    // ---- pass 1: issue all 16 loads first (max memory-level parallelism) ----
    f32x4 s4[8];
    float4 t4[8];
    #pragma unroll
    for (int i = 0; i < 8; ++i) {
        size_t off = (size_t)(g + 128 * i) * LL;
        s4[i] = __builtin_nontemporal_load((const f32x4*)(ps + off));  // xs: read-once
        t4[i] = *(const float4*)(pt + off);                            // xt: want L3
    }
    float4 es[8];
    float ss[4] = {0, 0, 0, 0}, sy[4] = {0, 0, 0, 0};
    #pragma unroll
    for (int i = 0; i < 8; ++i) {
        float4 e;
        e.x = __expf(s4[i].x); e.y = __expf(s4[i].y);
        e.z = __expf(s4[i].z); e.w = __expf(s4[i].w);
        es[i] = e;
        ss[0] += e.x; ss[1] += e.y; ss[2] += e.z; ss[3] += e.w;
        sy[0] += __expf(fmaxf(t4[i].x, mg)); sy[1] += __expf(fmaxf(t4[i].y, mg));
        sy[2] += __expf(fmaxf(t4[i].z, mg)); sy[3] += __expf(fmaxf(t4[i].w, mg));
    }
    // reduce across the 8 c-groups inside each wave (same-q lanes: lane = q + 8*gg)
    #pragma unroll
    for (int off = 8; off < 64; off <<= 1) {
        #pragma unroll
        for (int k = 0; k < 4; ++k) {
            ss[k] += __shfl_xor(ss[k], off, 64);
            sy[k] += __shfl_xor(sy[k], off, 64);
        }
    }
    if (lane < 8) {
        #pragma unroll
        for (int k = 0; k < 4; ++k) {
            s_red[0][w][lane][k] = ss[k];
            s_red[1][w][lane][k] = sy[k];
        }
    }
    __syncthreads();
    if (tid < 64) {
        int a  = tid >> 5;          // 0 = ss, 1 = sy
        int qq = (tid >> 2) & 7;
        int k  = tid & 3;
        float t = 0.f;
        #pragma unroll
        for (int ww = 0; ww < 16; ++ww) t += s_red[a][ww][qq][k];
        if (a == 0) s_sinv[qq][k] = 1.0f / t;      // 1/sum(exp(xs))
        else        s_blog[qq][k] = __logf(t);     // log(sum(exp(y)))
    }
    __syncthreads();
    float4 sinv = *(const float4*)&s_sinv[q][0];
    float4 blog = *(const float4*)&s_blog[q][0];

    // ---- pass 2: re-read xt (L3-resident), recompute y, store entropy ----
    float* po = out1 + (size_t)b * NPB + L0 + q * 4;
    float4 u4[8];
    #pragma unroll
    for (int i = 0; i < 8; ++i) {       // reverse: most-recent lines first
        size_t off = (size_t)(g + 128 * (7 - i)) * LL;
        u4[i] = *(const float4*)(pt + off);
    }
    float acc = 0.f;
    #pragma unroll
    for (int i = 0; i < 8; ++i) {
        int ci = 7 - i;
        size_t off = (size_t)(g + 128 * ci) * LL;
        f32x4 e;
        e.x = es[ci].x * sinv.x * (fmaxf(u4[i].x, mg) - blog.x);
        e.y = es[ci].y * sinv.y * (fmaxf(u4[i].y, mg) - blog.y);
        e.z = es[ci].z * sinv.z * (fmaxf(u4[i].z, mg) - blog.z);
        e.w = es[ci].w * sinv.w * (fmaxf(u4[i].w, mg) - blog.w);
        __builtin_nontemporal_store(e, (f32x4*)(po + off));
        acc += (e.x + e.y) + (e.z + e.w);
    }
    for (int off = 32; off; off >>= 1) acc += __shfl_down(acc, off, 64);
    if (lane == 0) wacc[w] = acc;
    __syncthreads();
    if (tid == 0) {
        double t = 0.0;
        #pragma unroll
        for (int ww = 0; ww < 16; ++ww) t += (double)wacc[ww];
        atomicAdd(lossAcc, t);
    }
}

__global__ void k_finalize(const double* __restrict__ lossAcc, float* __restrict__ out) {
    if (threadIdx.x == 0) out[0] = (float)(-lossAcc[0] / (double)(BB * LL));
}

extern "C" void kernel_launch(void* const* d_in, const int* in_sizes, int n_in,
                              void* d_out, int out_size, void* d_ws, size_t ws_size,
                              hipStream_t stream) {
    const float* x_ts = (const float*)d_in[2];  // source xs
    const float* x_st = (const float*)d_in[3];  // target xt
    float* out = (float*)d_out;

    double* sums    = (double*)d_ws;
    double* lossAcc = (double*)((char*)d_ws + 128);

    hipMemsetAsync(d_ws, 0, 256, stream);

    k_batch_sums<<<dim3(256, BB), 256, 0, stream>>>(x_st, sums);
    k_fused<<<dim3(LL / LT, BB), 1024, 0, stream>>>(x_ts, x_st, sums, out + 1, lossAcc);
    k_finalize<<<1, 64, 0, stream>>>(lossAcc, out);
}